// Round 3
// baseline (1359.812 us; speedup 1.0000x reference)
//
#include <hip/hip_runtime.h>
#include <hip/hip_bf16.h>
#include <stdint.h>

#define N_NODES 100000
#define N_EDGES 1600000
#define D_FEAT 32
#define CUT_K 320000   // int(N_EDGES * 0.2)
#define HIST_NB 1024   // blocks in hist pass; slices buffer = HIST_NB*256 u32

struct SelState { unsigned long long prefix; unsigned int k; };

__global__ void deg_kernel(const int* __restrict__ dst, int* __restrict__ deg, int E) {
    int e = blockIdx.x * blockDim.x + threadIdx.x;
    if (e < E) atomicAdd(&deg[dst[e]], 1);
}

__global__ void norm_kernel(const int* __restrict__ deg, float* __restrict__ nrm, int N) {
    int i = blockIdx.x * blockDim.x + threadIdx.x;
    if (i < N) nrm[i] = 1.0f / sqrtf(fmaxf((float)deg[i], 1.0f));
}

// single block: exclusive prefix sum of deg -> offs[0..N], and a second copy for cursors
__global__ void exscan_kernel(const int* __restrict__ deg, int* __restrict__ offs,
                              int* __restrict__ cursor, int N) {
    __shared__ int part[1024];
    int t = threadIdx.x;
    int chunk = (N + 1023) / 1024;
    int lo = t * chunk, hi = min(lo + chunk, N);
    int s = 0;
    for (int i = lo; i < hi; ++i) s += deg[i];
    part[t] = s;
    __syncthreads();
    for (int off = 1; off < 1024; off <<= 1) {
        int v = (t >= off) ? part[t - off] : 0;
        __syncthreads();
        part[t] += v;
        __syncthreads();
    }
    int run = part[t] - s;   // exclusive prefix of this chunk
    for (int i = lo; i < hi; ++i) {
        offs[i] = run; cursor[i] = run; run += deg[i];
    }
    if (hi == N) offs[N] = run;   // == E
}

// scatter edges into CSR-by-dst slots; keep original edge id for exact tie-break
__global__ void fill_kernel(const int* __restrict__ src, const int* __restrict__ dst,
                            int* __restrict__ cursor,
                            int* __restrict__ csr_src, int* __restrict__ csr_dst,
                            int* __restrict__ csr_eid, int E) {
    int e = blockIdx.x * blockDim.x + threadIdx.x;
    if (e >= E) return;
    int d = dst[e];
    int pos = atomicAdd(&cursor[d], 1);
    csr_src[pos] = src[e];
    csr_dst[pos] = d;
    csr_eid[pos] = e;
}

// nh = h / max(||h||,1e-12)  AND  hs = h * nrm   (fused, float4)
__global__ void rownorm_kernel(const float* __restrict__ h, float* __restrict__ nh,
                               float* __restrict__ hs, const float* __restrict__ nrm, int N) {
    int i = blockIdx.x * blockDim.x + threadIdx.x;
    if (i >= N) return;
    const float4* hp = (const float4*)(h + (size_t)i * D_FEAT);
    float4 v[8];
    float ss = 0.f;
#pragma unroll
    for (int q = 0; q < 8; ++q) {
        v[q] = hp[q];
        ss += v[q].x * v[q].x + v[q].y * v[q].y + v[q].z * v[q].z + v[q].w * v[q].w;
    }
    float inv = 1.0f / fmaxf(sqrtf(ss), 1e-12f);
    float sc = nrm[i];
    float4* op = (float4*)(nh + (size_t)i * D_FEAT);
    float4* sp = (float4*)(hs + (size_t)i * D_FEAT);
#pragma unroll
    for (int q = 0; q < 8; ++q) {
        float4 ov = v[q];
        float4 sv = v[q];
        ov.x *= inv; ov.y *= inv; ov.z *= inv; ov.w *= inv;
        sv.x *= sc;  sv.y *= sc;  sv.z *= sc;  sv.w *= sc;
        op[q] = ov;
        sp[q] = sv;
    }
}

// keys[p] = (sortable(cos_p) << 32) | orig_eid  -- distinct keys, exact top_k tie-break
__global__ void coskey_kernel(const float* __restrict__ nh, const int* __restrict__ csr_src,
                              const int* __restrict__ csr_dst, const int* __restrict__ csr_eid,
                              unsigned long long* __restrict__ keys, int E) {
    int p = blockIdx.x * blockDim.x + threadIdx.x;
    if (p >= E) return;
    const float4* a = (const float4*)(nh + (size_t)csr_src[p] * D_FEAT);
    const float4* b = (const float4*)(nh + (size_t)csr_dst[p] * D_FEAT);
    float s = 0.f;
#pragma unroll
    for (int q = 0; q < 8; ++q) {
        float4 x = a[q], y = b[q];
        s += x.x * y.x + x.y * y.y + x.z * y.z + x.w * y.w;
    }
    unsigned int u = __float_as_uint(s);
    unsigned int so = (u & 0x80000000u) ? ~u : (u | 0x80000000u);
    keys[p] = ((unsigned long long)so << 32) | (unsigned int)csr_eid[p];
}

__global__ void initsel_kernel(SelState* st) { st->prefix = 0ull; st->k = CUT_K; }

// radix-select histogram pass: 8-bit digit, MSB first, per-wave LDS hists,
// per-block non-atomic slice writes (no global atomics at all)
__global__ void hist8_kernel(const unsigned long long* __restrict__ keys, int E,
                             unsigned int* __restrict__ slices,
                             const SelState* __restrict__ st, int pass) {
    __shared__ unsigned int lh[4][256];
    int t = threadIdx.x;
#pragma unroll
    for (int w = 0; w < 4; ++w) lh[w][t] = 0u;
    __syncthreads();
    unsigned long long prefix = st->prefix;
    int wave = t >> 6;
    int dshift = 56 - 8 * pass;
    int pshift = 64 - 8 * pass;   // valid only when pass>0
    int stride = gridDim.x * blockDim.x;
    for (int e = blockIdx.x * blockDim.x + t; e < E; e += stride) {
        unsigned long long key = keys[e];
        bool ok = (pass == 0) || ((key >> pshift) == prefix);
        if (ok) atomicAdd(&lh[wave][(unsigned int)((key >> dshift) & 0xFFull)], 1u);
    }
    __syncthreads();
    slices[(size_t)blockIdx.x * 256 + t] = lh[0][t] + lh[1][t] + lh[2][t] + lh[3][t];
}

// single block of 256 threads: reduce slices, scan 256 bins, pick digit at rank k
__global__ void scan8_kernel(const unsigned int* __restrict__ slices,
                             SelState* __restrict__ st) {
    __shared__ unsigned int buf[256];
    int t = threadIdx.x;
    unsigned int k = st->k;            // read before any write
    unsigned int s = 0;
#pragma unroll 8
    for (int b = 0; b < HIST_NB; ++b) s += slices[(size_t)b * 256 + t];
    buf[t] = s;
    __syncthreads();
    for (int off = 1; off < 256; off <<= 1) {
        unsigned int v = (t >= off) ? buf[t - off] : 0u;
        __syncthreads();
        buf[t] += v;
        __syncthreads();
    }
    unsigned int incl = buf[t];
    unsigned int excl = incl - s;
    if (excl < k && k <= incl) {       // exactly one thread wins
        st->prefix = (st->prefix << 8) | (unsigned long long)t;
        st->k = k - excl;
    }
}

// pull aggregation: one 32-lane group per node walks its CSR segment.
// out[n][j] = nrm[n] * sum_{p in seg, keys[p] > kth} hs[csr_src[p]][j]
__global__ void aggregate_csr_kernel(const float* __restrict__ hs, float* __restrict__ h_out,
                                     const int* __restrict__ offs, const int* __restrict__ csr_src,
                                     const unsigned long long* __restrict__ keys,
                                     const SelState* __restrict__ st,
                                     const float* __restrict__ nrm, int N) {
    unsigned long long kth = st->prefix;   // cut_k-th smallest composite key
    int g = blockIdx.x * 8 + (threadIdx.x >> 5);
    int j = threadIdx.x & 31;
    if (g >= N) return;
    int lo = offs[g], hi = offs[g + 1];
    float acc = 0.f;
    for (int p = lo; p < hi; ++p) {
        if (keys[p] > kth) {
            acc += hs[(size_t)csr_src[p] * D_FEAT + j];
        }
    }
    h_out[(size_t)g * D_FEAT + j] = acc * nrm[g];
}

// out = h @ W^T ; W is [32,32] row-major; stage W transposed in LDS (pad 33, conflict-free)
__global__ void fc_kernel(const float* __restrict__ h, const float* __restrict__ W,
                          float* __restrict__ out, int N) {
    __shared__ float Wt[32][33];
    int t = threadIdx.x;
    for (int i = t; i < 1024; i += 256) Wt[i & 31][i >> 5] = W[i];
    __syncthreads();
    int node = blockIdx.x * 8 + (t >> 5);
    if (node >= N) return;
    int o = t & 31;
    const float* hr = h + (size_t)node * D_FEAT;
    float acc = 0.f;
#pragma unroll
    for (int j = 0; j < 32; ++j) acc += hr[j] * Wt[j][o];
    out[(size_t)node * D_FEAT + o] = acc;
}

extern "C" void kernel_launch(void* const* d_in, const int* in_sizes, int n_in,
                              void* d_out, int out_size, void* d_ws, size_t ws_size,
                              hipStream_t stream) {
    const float* features = (const float*)d_in[0];
    const float* W        = (const float*)d_in[1];
    const int*   src      = (const int*)d_in[2];
    const int*   dst      = (const int*)d_in[3];
    float*       out      = (float*)d_out;

    char* ws = (char*)d_ws;
    size_t o = 0;
    auto take = [&](size_t bytes) -> char* {
        char* p = ws + o;
        o += (bytes + 255) & ~(size_t)255;
        return p;
    };
    int*                deg     = (int*)take((size_t)N_NODES * 4);
    float*              nrm     = (float*)take((size_t)N_NODES * 4);
    int*                offs    = (int*)take((size_t)(N_NODES + 1) * 4);
    int*                cursor  = (int*)take((size_t)N_NODES * 4);
    int*                csr_src = (int*)take((size_t)N_EDGES * 4);
    int*                csr_dst = (int*)take((size_t)N_EDGES * 4);
    int*                csr_eid = (int*)take((size_t)N_EDGES * 4);
    float*              hA      = (float*)take((size_t)N_NODES * D_FEAT * 4);
    float*              hB      = (float*)take((size_t)N_NODES * D_FEAT * 4);
    float*              nh      = (float*)take((size_t)N_NODES * D_FEAT * 4);
    float*              hs      = (float*)take((size_t)N_NODES * D_FEAT * 4);
    unsigned long long* keys    = (unsigned long long*)take((size_t)N_EDGES * 8);
    unsigned int*       slices  = (unsigned int*)take((size_t)HIST_NB * 256 * 4);
    SelState*           st      = (SelState*)take(256);

    hipMemsetAsync(deg, 0, (size_t)N_NODES * 4, stream);

    deg_kernel<<<(N_EDGES + 255) / 256, 256, 0, stream>>>(dst, deg, N_EDGES);
    norm_kernel<<<(N_NODES + 255) / 256, 256, 0, stream>>>(deg, nrm, N_NODES);
    exscan_kernel<<<1, 1024, 0, stream>>>(deg, offs, cursor, N_NODES);
    fill_kernel<<<(N_EDGES + 255) / 256, 256, 0, stream>>>(src, dst, cursor,
                                                           csr_src, csr_dst, csr_eid, N_EDGES);

    const float* hin = features;
    float* houts[2] = { hA, hB };
    for (int hop = 0; hop < 2; ++hop) {
        float* hout = houts[hop];
        rownorm_kernel<<<(N_NODES + 255) / 256, 256, 0, stream>>>(hin, nh, hs, nrm, N_NODES);
        coskey_kernel<<<(N_EDGES + 255) / 256, 256, 0, stream>>>(nh, csr_src, csr_dst, csr_eid,
                                                                 keys, N_EDGES);
        initsel_kernel<<<1, 1, 0, stream>>>(st);
        for (int pass = 0; pass < 8; ++pass) {
            hist8_kernel<<<HIST_NB, 256, 0, stream>>>(keys, N_EDGES, slices, st, pass);
            scan8_kernel<<<1, 256, 0, stream>>>(slices, st);
        }
        aggregate_csr_kernel<<<(N_NODES + 7) / 8, 256, 0, stream>>>(
            hs, hout, offs, csr_src, keys, st, nrm, N_NODES);
        hin = hout;
    }
    fc_kernel<<<(N_NODES + 7) / 8, 256, 0, stream>>>(hin, W, out, N_NODES);
}

// Round 4
// 1288.013 us; speedup vs baseline: 1.0557x; 1.0557x over previous
//
#include <hip/hip_runtime.h>
#include <hip/hip_bf16.h>
#include <stdint.h>

#define N_NODES 100000
#define N_EDGES 1600000
#define D_FEAT 32
#define CUT_K 320000   // int(N_EDGES * 0.2)
#define HIST_NB 1024   // grid-stride blocks for edge-volume kernels
#define SCAN_NB ((N_NODES + 255) / 256)   // 391

struct SelState { unsigned long long prefix; unsigned int k; unsigned int cnt[8]; };

__global__ void deg_kernel(const int* __restrict__ dst, int* __restrict__ deg, int E) {
    int e = blockIdx.x * blockDim.x + threadIdx.x;
    if (e < E) atomicAdd(&deg[dst[e]], 1);
}

__global__ void norm_kernel(const int* __restrict__ deg, float* __restrict__ nrm, int N) {
    int i = blockIdx.x * blockDim.x + threadIdx.x;
    if (i < N) nrm[i] = 1.0f / sqrtf(fmaxf((float)deg[i], 1.0f));
}

// ---- parallel exclusive scan of deg (3 kernels) ----
__global__ void blocksum_kernel(const int* __restrict__ deg, int* __restrict__ bsum, int N) {
    int i = blockIdx.x * 256 + threadIdx.x;
    int v = (i < N) ? deg[i] : 0;
#pragma unroll
    for (int off = 32; off > 0; off >>= 1) v += __shfl_down(v, off, 64);
    __shared__ int ws4[4];
    if ((threadIdx.x & 63) == 0) ws4[threadIdx.x >> 6] = v;
    __syncthreads();
    if (threadIdx.x == 0) bsum[blockIdx.x] = ws4[0] + ws4[1] + ws4[2] + ws4[3];
}

__global__ void scanpartial_kernel(const int* __restrict__ bsum, int* __restrict__ boff, int B) {
    __shared__ int buf[512];
    int t = threadIdx.x;
    int v = (t < B) ? bsum[t] : 0;
    buf[t] = v;
    __syncthreads();
    for (int off = 1; off < 512; off <<= 1) {
        int u = (t >= off) ? buf[t - off] : 0;
        __syncthreads();
        buf[t] += u;
        __syncthreads();
    }
    if (t < B) boff[t] = buf[t] - v;   // exclusive
}

__global__ void writeoffs_kernel(const int* __restrict__ deg, const int* __restrict__ boff,
                                 int* __restrict__ offs, int* __restrict__ cursor, int N) {
    __shared__ int buf[256];
    int t = threadIdx.x;
    int i = blockIdx.x * 256 + t;
    int v = (i < N) ? deg[i] : 0;
    buf[t] = v;
    __syncthreads();
    for (int off = 1; off < 256; off <<= 1) {
        int u = (t >= off) ? buf[t - off] : 0;
        __syncthreads();
        buf[t] += u;
        __syncthreads();
    }
    int ex = buf[t] - v + boff[blockIdx.x];
    if (i < N) { offs[i] = ex; cursor[i] = ex; }
    if (i == N - 1) offs[N] = ex + v;   // == E
}

// scatter edges into CSR-by-dst slots; keep original edge id for exact tie-break
__global__ void fill_kernel(const int* __restrict__ src, const int* __restrict__ dst,
                            int* __restrict__ cursor,
                            int* __restrict__ csr_src, int* __restrict__ csr_dst,
                            int* __restrict__ csr_eid, int E) {
    int e = blockIdx.x * blockDim.x + threadIdx.x;
    if (e >= E) return;
    int d = dst[e];
    int pos = atomicAdd(&cursor[d], 1);
    csr_src[pos] = src[e];
    csr_dst[pos] = d;
    csr_eid[pos] = e;
}

// nh = h / max(||h||,1e-12)  AND  hs = h * nrm   (fused, float4)
__global__ void rownorm_kernel(const float* __restrict__ h, float* __restrict__ nh,
                               float* __restrict__ hs, const float* __restrict__ nrm, int N) {
    int i = blockIdx.x * blockDim.x + threadIdx.x;
    if (i >= N) return;
    const float4* hp = (const float4*)(h + (size_t)i * D_FEAT);
    float4 v[8];
    float ss = 0.f;
#pragma unroll
    for (int q = 0; q < 8; ++q) {
        v[q] = hp[q];
        ss += v[q].x * v[q].x + v[q].y * v[q].y + v[q].z * v[q].z + v[q].w * v[q].w;
    }
    float inv = 1.0f / fmaxf(sqrtf(ss), 1e-12f);
    float sc = nrm[i];
    float4* op = (float4*)(nh + (size_t)i * D_FEAT);
    float4* sp = (float4*)(hs + (size_t)i * D_FEAT);
#pragma unroll
    for (int q = 0; q < 8; ++q) {
        float4 ov = v[q];
        float4 sv = v[q];
        ov.x *= inv; ov.y *= inv; ov.z *= inv; ov.w *= inv;
        sv.x *= sc;  sv.y *= sc;  sv.z *= sc;  sv.w *= sc;
        op[q] = ov;
        sp[q] = sv;
    }
}

__global__ void initsel_kernel(SelState* st) {
    st->prefix = 0ull; st->k = CUT_K;
#pragma unroll
    for (int i = 0; i < 8; ++i) st->cnt[i] = 0u;
}

// keys[p] = (sortable(cos_p) << 32) | orig_eid; fused pass-0 histogram (top 8 bits)
__global__ void coskey_kernel(const float* __restrict__ nh, const int* __restrict__ csr_src,
                              const int* __restrict__ csr_dst, const int* __restrict__ csr_eid,
                              unsigned long long* __restrict__ keys,
                              unsigned int* __restrict__ ghist, int E) {
    __shared__ unsigned int lh[4][256];
    int t = threadIdx.x;
#pragma unroll
    for (int w = 0; w < 4; ++w) lh[w][t] = 0u;
    __syncthreads();
    int wave = t >> 6;
    int stride = gridDim.x * blockDim.x;
    for (int p = blockIdx.x * blockDim.x + t; p < E; p += stride) {
        const float4* a = (const float4*)(nh + (size_t)csr_src[p] * D_FEAT);
        const float4* b = (const float4*)(nh + (size_t)csr_dst[p] * D_FEAT);
        float s = 0.f;
#pragma unroll
        for (int q = 0; q < 8; ++q) {
            float4 x = a[q], y = b[q];
            s += x.x * y.x + x.y * y.y + x.z * y.z + x.w * y.w;
        }
        unsigned int u = __float_as_uint(s);
        unsigned int so = (u & 0x80000000u) ? ~u : (u | 0x80000000u);
        unsigned long long key = ((unsigned long long)so << 32) | (unsigned int)csr_eid[p];
        keys[p] = key;
        atomicAdd(&lh[wave][(unsigned int)(key >> 56)], 1u);
    }
    __syncthreads();
    unsigned int tot = lh[0][t] + lh[1][t] + lh[2][t] + lh[3][t];
    if (tot) atomicAdd(&ghist[t], tot);
}

// compacting radix pass p (1..7): filter by current prefix, histogram next digit,
// wave-aggregated append of survivors to `out` via st->cnt[pass]
__global__ void histc_kernel(const unsigned long long* __restrict__ in,
                             unsigned long long* __restrict__ out,
                             SelState* __restrict__ st,
                             unsigned int* __restrict__ ghist, int pass) {
    __shared__ unsigned int lh[4][256];
    int t = threadIdx.x;
#pragma unroll
    for (int w = 0; w < 4; ++w) lh[w][t] = 0u;
    __syncthreads();
    unsigned long long prefix = st->prefix;
    unsigned int n = (pass == 1) ? (unsigned int)N_EDGES : st->cnt[pass - 1];
    unsigned int* cursor = &st->cnt[pass];
    int wave = t >> 6;
    int lane = t & 63;
    int fshift = 64 - 8 * pass;
    int dshift = 56 - 8 * pass;
    unsigned int stride = gridDim.x * blockDim.x;
    unsigned int gid = blockIdx.x * blockDim.x + t;
    unsigned int iters = (n + stride - 1) / stride;
    for (unsigned int it = 0; it < iters; ++it) {
        unsigned int i = gid + it * stride;
        bool valid = i < n;
        unsigned long long key = valid ? in[i] : 0ull;
        bool ok = valid && ((key >> fshift) == prefix);
        if (ok) atomicAdd(&lh[wave][(unsigned int)((key >> dshift) & 0xFFull)], 1u);
        unsigned long long mask = __ballot(ok);
        if (mask) {
            int leader = __ffsll((unsigned long long)mask) - 1;
            unsigned int base = 0;
            if (lane == leader) base = atomicAdd(cursor, (unsigned int)__popcll(mask));
            base = __shfl(base, leader, 64);
            if (ok) out[base + __popcll(mask & ((1ull << lane) - 1ull))] = key;
        }
    }
    __syncthreads();
    unsigned int tot = lh[0][t] + lh[1][t] + lh[2][t] + lh[3][t];
    if (tot) atomicAdd(&ghist[t], tot);
}

// single block of 256: scan 256-bin global hist, pick digit at rank k, zero hist
__global__ void scan8_kernel(unsigned int* __restrict__ ghist, SelState* __restrict__ st) {
    __shared__ unsigned int buf[256];
    int t = threadIdx.x;
    unsigned int k = st->k;            // read before any write
    unsigned int s = ghist[t];
    buf[t] = s;
    __syncthreads();
    for (int off = 1; off < 256; off <<= 1) {
        unsigned int v = (t >= off) ? buf[t - off] : 0u;
        __syncthreads();
        buf[t] += v;
        __syncthreads();
    }
    unsigned int incl = buf[t];
    unsigned int excl = incl - s;
    if (excl < k && k <= incl) {       // exactly one thread wins
        st->prefix = (st->prefix << 8) | (unsigned long long)t;
        st->k = k - excl;
    }
    ghist[t] = 0u;                     // ready for next pass/hop
}

// pull aggregation: one 32-lane group per node walks its CSR segment.
__global__ void aggregate_csr_kernel(const float* __restrict__ hs, float* __restrict__ h_out,
                                     const int* __restrict__ offs, const int* __restrict__ csr_src,
                                     const unsigned long long* __restrict__ keys,
                                     const SelState* __restrict__ st,
                                     const float* __restrict__ nrm, int N) {
    unsigned long long kth = st->prefix;   // cut_k-th smallest composite key
    int g = blockIdx.x * 8 + (threadIdx.x >> 5);
    int j = threadIdx.x & 31;
    if (g >= N) return;
    int lo = offs[g], hi = offs[g + 1];
    float acc = 0.f;
    for (int p = lo; p < hi; ++p) {
        if (keys[p] > kth) {
            acc += hs[(size_t)csr_src[p] * D_FEAT + j];
        }
    }
    h_out[(size_t)g * D_FEAT + j] = acc * nrm[g];
}

// out = h @ W^T ; stage W transposed in LDS (pad 33, conflict-free)
__global__ void fc_kernel(const float* __restrict__ h, const float* __restrict__ W,
                          float* __restrict__ out, int N) {
    __shared__ float Wt[32][33];
    int t = threadIdx.x;
    for (int i = t; i < 1024; i += 256) Wt[i & 31][i >> 5] = W[i];
    __syncthreads();
    int node = blockIdx.x * 8 + (t >> 5);
    if (node >= N) return;
    int o = t & 31;
    const float* hr = h + (size_t)node * D_FEAT;
    float acc = 0.f;
#pragma unroll
    for (int j = 0; j < 32; ++j) acc += hr[j] * Wt[j][o];
    out[(size_t)node * D_FEAT + o] = acc;
}

extern "C" void kernel_launch(void* const* d_in, const int* in_sizes, int n_in,
                              void* d_out, int out_size, void* d_ws, size_t ws_size,
                              hipStream_t stream) {
    const float* features = (const float*)d_in[0];
    const float* W        = (const float*)d_in[1];
    const int*   src      = (const int*)d_in[2];
    const int*   dst      = (const int*)d_in[3];
    float*       out      = (float*)d_out;

    char* ws = (char*)d_ws;
    size_t o = 0;
    auto take = [&](size_t bytes) -> char* {
        char* p = ws + o;
        o += (bytes + 255) & ~(size_t)255;
        return p;
    };
    int*                deg     = (int*)take((size_t)N_NODES * 4);
    float*              nrm     = (float*)take((size_t)N_NODES * 4);
    int*                offs    = (int*)take((size_t)(N_NODES + 1) * 4);
    int*                cursor  = (int*)take((size_t)N_NODES * 4);
    int*                csr_src = (int*)take((size_t)N_EDGES * 4);
    int*                csr_dst = (int*)take((size_t)N_EDGES * 4);
    int*                csr_eid = (int*)take((size_t)N_EDGES * 4);
    float*              hA      = (float*)take((size_t)N_NODES * D_FEAT * 4);
    float*              hB      = (float*)take((size_t)N_NODES * D_FEAT * 4);
    float*              nh      = (float*)take((size_t)N_NODES * D_FEAT * 4);
    float*              hs      = (float*)take((size_t)N_NODES * D_FEAT * 4);
    unsigned long long* keys    = (unsigned long long*)take((size_t)N_EDGES * 8);
    unsigned int*       ghist   = (unsigned int*)take((size_t)256 * 4);
    SelState*           st      = (SelState*)take(256);
    int*                bsum    = (int*)take((size_t)SCAN_NB * 4);
    int*                boff    = (int*)take((size_t)SCAN_NB * 4);

    // candidate buffers alias memory that is dead during the radix passes:
    // nh is dead after coskey; hB is written only by hop-2 aggregate (after selection)
    unsigned long long* candA = (unsigned long long*)nh;   // 12.8 MB == E*8
    unsigned long long* candB = (unsigned long long*)hB;   // 12.8 MB == E*8

    hipMemsetAsync(deg, 0, (size_t)N_NODES * 4, stream);
    hipMemsetAsync(ghist, 0, (size_t)256 * 4, stream);

    deg_kernel<<<(N_EDGES + 255) / 256, 256, 0, stream>>>(dst, deg, N_EDGES);
    norm_kernel<<<(N_NODES + 255) / 256, 256, 0, stream>>>(deg, nrm, N_NODES);
    blocksum_kernel<<<SCAN_NB, 256, 0, stream>>>(deg, bsum, N_NODES);
    scanpartial_kernel<<<1, 512, 0, stream>>>(bsum, boff, SCAN_NB);
    writeoffs_kernel<<<SCAN_NB, 256, 0, stream>>>(deg, boff, offs, cursor, N_NODES);
    fill_kernel<<<(N_EDGES + 255) / 256, 256, 0, stream>>>(src, dst, cursor,
                                                           csr_src, csr_dst, csr_eid, N_EDGES);

    const float* hin = features;
    float* houts[2] = { hA, hB };
    for (int hop = 0; hop < 2; ++hop) {
        float* hout = houts[hop];
        rownorm_kernel<<<(N_NODES + 255) / 256, 256, 0, stream>>>(hin, nh, hs, nrm, N_NODES);
        initsel_kernel<<<1, 1, 0, stream>>>(st);
        coskey_kernel<<<HIST_NB, 256, 0, stream>>>(nh, csr_src, csr_dst, csr_eid,
                                                   keys, ghist, N_EDGES);
        scan8_kernel<<<1, 256, 0, stream>>>(ghist, st);   // digit 0
        for (int pass = 1; pass < 8; ++pass) {
            const unsigned long long* in =
                (pass == 1) ? keys : ((pass & 1) ? candB : candA);
            unsigned long long* outc = (pass & 1) ? candA : candB;
            histc_kernel<<<HIST_NB, 256, 0, stream>>>(in, outc, st, ghist, pass);
            scan8_kernel<<<1, 256, 0, stream>>>(ghist, st);
        }
        aggregate_csr_kernel<<<(N_NODES + 7) / 8, 256, 0, stream>>>(
            hs, hout, offs, csr_src, keys, st, nrm, N_NODES);
        hin = hout;
    }
    fc_kernel<<<(N_NODES + 7) / 8, 256, 0, stream>>>(hin, W, out, N_NODES);
}

// Round 5
// 719.189 us; speedup vs baseline: 1.8908x; 1.7909x over previous
//
#include <hip/hip_runtime.h>
#include <hip/hip_bf16.h>
#include <stdint.h>

#define N_NODES 100000
#define N_EDGES 1600000
#define D_FEAT 32
#define CUT_K 320000        // int(N_EDGES * 0.2)
#define HIST_NB 1024        // grid-stride blocks for coskey
#define HC_NB 1000          // histc blocks; E = HC_NB * HC_SLICE exactly
#define HC_SLICE 1600
#define SCAN_NB ((N_NODES + 255) / 256)   // 391

struct SelState { unsigned long long prefix; unsigned int k; };

__global__ void deg_kernel(const int* __restrict__ dst, int* __restrict__ deg, int E) {
    int e = blockIdx.x * blockDim.x + threadIdx.x;
    if (e < E) atomicAdd(&deg[dst[e]], 1);
}

__global__ void norm_kernel(const int* __restrict__ deg, float* __restrict__ nrm, int N) {
    int i = blockIdx.x * blockDim.x + threadIdx.x;
    if (i < N) nrm[i] = 1.0f / sqrtf(fmaxf((float)deg[i], 1.0f));
}

// ---- parallel exclusive scan of deg (3 kernels) ----
__global__ void blocksum_kernel(const int* __restrict__ deg, int* __restrict__ bsum, int N) {
    int i = blockIdx.x * 256 + threadIdx.x;
    int v = (i < N) ? deg[i] : 0;
#pragma unroll
    for (int off = 32; off > 0; off >>= 1) v += __shfl_down(v, off, 64);
    __shared__ int ws4[4];
    if ((threadIdx.x & 63) == 0) ws4[threadIdx.x >> 6] = v;
    __syncthreads();
    if (threadIdx.x == 0) bsum[blockIdx.x] = ws4[0] + ws4[1] + ws4[2] + ws4[3];
}

__global__ void scanpartial_kernel(const int* __restrict__ bsum, int* __restrict__ boff, int B) {
    __shared__ int buf[512];
    int t = threadIdx.x;
    int v = (t < B) ? bsum[t] : 0;
    buf[t] = v;
    __syncthreads();
    for (int off = 1; off < 512; off <<= 1) {
        int u = (t >= off) ? buf[t - off] : 0;
        __syncthreads();
        buf[t] += u;
        __syncthreads();
    }
    if (t < B) boff[t] = buf[t] - v;   // exclusive
}

__global__ void writeoffs_kernel(const int* __restrict__ deg, const int* __restrict__ boff,
                                 int* __restrict__ offs, int* __restrict__ cursor, int N) {
    __shared__ int buf[256];
    int t = threadIdx.x;
    int i = blockIdx.x * 256 + t;
    int v = (i < N) ? deg[i] : 0;
    buf[t] = v;
    __syncthreads();
    for (int off = 1; off < 256; off <<= 1) {
        int u = (t >= off) ? buf[t - off] : 0;
        __syncthreads();
        buf[t] += u;
        __syncthreads();
    }
    int ex = buf[t] - v + boff[blockIdx.x];
    if (i < N) { offs[i] = ex; cursor[i] = ex; }
    if (i == N - 1) offs[N] = ex + v;   // == E
}

// scatter edges into CSR-by-dst slots; keep original edge id for exact tie-break
__global__ void fill_kernel(const int* __restrict__ src, const int* __restrict__ dst,
                            int* __restrict__ cursor,
                            int* __restrict__ csr_src, int* __restrict__ csr_dst,
                            int* __restrict__ csr_eid, int E) {
    int e = blockIdx.x * blockDim.x + threadIdx.x;
    if (e >= E) return;
    int d = dst[e];
    int pos = atomicAdd(&cursor[d], 1);
    csr_src[pos] = src[e];
    csr_dst[pos] = d;
    csr_eid[pos] = e;
}

// nh = h / max(||h||,1e-12)  AND  hs = h * nrm   (fused, float4)
__global__ void rownorm_kernel(const float* __restrict__ h, float* __restrict__ nh,
                               float* __restrict__ hs, const float* __restrict__ nrm, int N) {
    int i = blockIdx.x * blockDim.x + threadIdx.x;
    if (i >= N) return;
    const float4* hp = (const float4*)(h + (size_t)i * D_FEAT);
    float4 v[8];
    float ss = 0.f;
#pragma unroll
    for (int q = 0; q < 8; ++q) {
        v[q] = hp[q];
        ss += v[q].x * v[q].x + v[q].y * v[q].y + v[q].z * v[q].z + v[q].w * v[q].w;
    }
    float inv = 1.0f / fmaxf(sqrtf(ss), 1e-12f);
    float sc = nrm[i];
    float4* op = (float4*)(nh + (size_t)i * D_FEAT);
    float4* sp = (float4*)(hs + (size_t)i * D_FEAT);
#pragma unroll
    for (int q = 0; q < 8; ++q) {
        float4 ov = v[q];
        float4 sv = v[q];
        ov.x *= inv; ov.y *= inv; ov.z *= inv; ov.w *= inv;
        sv.x *= sc;  sv.y *= sc;  sv.z *= sc;  sv.w *= sc;
        op[q] = ov;
        sp[q] = sv;
    }
}

__global__ void initsel_kernel(SelState* st) { st->prefix = 0ull; st->k = CUT_K; }

// keys[p] = (sortable(cos_p) << 32) | orig_eid; fused pass-0 histogram (top 8 bits)
__global__ void coskey_kernel(const float* __restrict__ nh, const int* __restrict__ csr_src,
                              const int* __restrict__ csr_dst, const int* __restrict__ csr_eid,
                              unsigned long long* __restrict__ keys,
                              unsigned int* __restrict__ ghist, int E) {
    __shared__ unsigned int lh[4][256];
    int t = threadIdx.x;
#pragma unroll
    for (int w = 0; w < 4; ++w) lh[w][t] = 0u;
    __syncthreads();
    int wave = t >> 6;
    int stride = gridDim.x * blockDim.x;
    for (int p = blockIdx.x * blockDim.x + t; p < E; p += stride) {
        const float4* a = (const float4*)(nh + (size_t)csr_src[p] * D_FEAT);
        const float4* b = (const float4*)(nh + (size_t)csr_dst[p] * D_FEAT);
        float s = 0.f;
#pragma unroll
        for (int q = 0; q < 8; ++q) {
            float4 x = a[q], y = b[q];
            s += x.x * y.x + x.y * y.y + x.z * y.z + x.w * y.w;
        }
        unsigned int u = __float_as_uint(s);
        unsigned int so = (u & 0x80000000u) ? ~u : (u | 0x80000000u);
        unsigned long long key = ((unsigned long long)so << 32) | (unsigned int)csr_eid[p];
        keys[p] = key;
        atomicAdd(&lh[wave][(unsigned int)(key >> 56)], 1u);
    }
    __syncthreads();
    unsigned int tot = lh[0][t] + lh[1][t] + lh[2][t] + lh[3][t];
    if (tot) atomicAdd(&ghist[t], tot);
}

// compacting radix pass p (1..7), slice-deterministic, NO global atomics except
// the 256-bin ghist merge. Block b: input slice b (dense keys for pass 1),
// survivors appended to its private output slice via an LDS cursor.
__global__ void histc_kernel(const unsigned long long* __restrict__ in,
                             const int* __restrict__ cnt_in,      // null => dense (pass 1)
                             unsigned long long* __restrict__ out,
                             int* __restrict__ cnt_out,
                             const SelState* __restrict__ st,
                             unsigned int* __restrict__ ghist, int pass) {
    __shared__ unsigned int lh[4][256];
    __shared__ unsigned int lcnt;
    int t = threadIdx.x, b = blockIdx.x;
#pragma unroll
    for (int w = 0; w < 4; ++w) lh[w][t] = 0u;
    if (t == 0) lcnt = 0u;
    __syncthreads();
    unsigned long long prefix = st->prefix;
    int n = cnt_in ? cnt_in[b] : HC_SLICE;
    const unsigned long long* sin = in + (size_t)b * HC_SLICE;
    unsigned long long* sout = out + (size_t)b * HC_SLICE;
    int wave = t >> 6;
    int fshift = 64 - 8 * pass;
    int dshift = 56 - 8 * pass;
    for (int i = t; i < n; i += 256) {
        unsigned long long key = sin[i];
        if ((key >> fshift) == prefix) {
            atomicAdd(&lh[wave][(unsigned int)((key >> dshift) & 0xFFull)], 1u);
            unsigned int slot = atomicAdd(&lcnt, 1u);   // LDS atomic, block-local
            sout[slot] = key;
        }
    }
    __syncthreads();
    unsigned int tot = lh[0][t] + lh[1][t] + lh[2][t] + lh[3][t];
    if (tot) atomicAdd(&ghist[t], tot);
    if (t == 0) cnt_out[b] = (int)lcnt;
}

// single block of 256: scan 256-bin global hist, pick digit at rank k, zero hist
__global__ void scan8_kernel(unsigned int* __restrict__ ghist, SelState* __restrict__ st) {
    __shared__ unsigned int buf[256];
    int t = threadIdx.x;
    unsigned int k = st->k;            // read before any write
    unsigned int s = ghist[t];
    buf[t] = s;
    __syncthreads();
    for (int off = 1; off < 256; off <<= 1) {
        unsigned int v = (t >= off) ? buf[t - off] : 0u;
        __syncthreads();
        buf[t] += v;
        __syncthreads();
    }
    unsigned int incl = buf[t];
    unsigned int excl = incl - s;
    if (excl < k && k <= incl) {       // exactly one thread wins
        st->prefix = (st->prefix << 8) | (unsigned long long)t;
        st->k = k - excl;
    }
    ghist[t] = 0u;                     // ready for next pass/hop
}

// pull aggregation: one 32-lane group per node walks its CSR segment.
__global__ void aggregate_csr_kernel(const float* __restrict__ hs, float* __restrict__ h_out,
                                     const int* __restrict__ offs, const int* __restrict__ csr_src,
                                     const unsigned long long* __restrict__ keys,
                                     const SelState* __restrict__ st,
                                     const float* __restrict__ nrm, int N) {
    unsigned long long kth = st->prefix;   // cut_k-th smallest composite key
    int g = blockIdx.x * 8 + (threadIdx.x >> 5);
    int j = threadIdx.x & 31;
    if (g >= N) return;
    int lo = offs[g], hi = offs[g + 1];
    float acc = 0.f;
    for (int p = lo; p < hi; ++p) {
        if (keys[p] > kth) {
            acc += hs[(size_t)csr_src[p] * D_FEAT + j];
        }
    }
    h_out[(size_t)g * D_FEAT + j] = acc * nrm[g];
}

// out = h @ W^T ; stage W transposed in LDS (pad 33, conflict-free)
__global__ void fc_kernel(const float* __restrict__ h, const float* __restrict__ W,
                          float* __restrict__ out, int N) {
    __shared__ float Wt[32][33];
    int t = threadIdx.x;
    for (int i = t; i < 1024; i += 256) Wt[i & 31][i >> 5] = W[i];
    __syncthreads();
    int node = blockIdx.x * 8 + (t >> 5);
    if (node >= N) return;
    int o = t & 31;
    const float* hr = h + (size_t)node * D_FEAT;
    float acc = 0.f;
#pragma unroll
    for (int j = 0; j < 32; ++j) acc += hr[j] * Wt[j][o];
    out[(size_t)node * D_FEAT + o] = acc;
}

extern "C" void kernel_launch(void* const* d_in, const int* in_sizes, int n_in,
                              void* d_out, int out_size, void* d_ws, size_t ws_size,
                              hipStream_t stream) {
    const float* features = (const float*)d_in[0];
    const float* W        = (const float*)d_in[1];
    const int*   src      = (const int*)d_in[2];
    const int*   dst      = (const int*)d_in[3];
    float*       out      = (float*)d_out;

    char* ws = (char*)d_ws;
    size_t o = 0;
    auto take = [&](size_t bytes) -> char* {
        char* p = ws + o;
        o += (bytes + 255) & ~(size_t)255;
        return p;
    };
    int*                deg     = (int*)take((size_t)N_NODES * 4);
    float*              nrm     = (float*)take((size_t)N_NODES * 4);
    int*                offs    = (int*)take((size_t)(N_NODES + 1) * 4);
    int*                cursor  = (int*)take((size_t)N_NODES * 4);
    int*                csr_src = (int*)take((size_t)N_EDGES * 4);
    int*                csr_dst = (int*)take((size_t)N_EDGES * 4);
    int*                csr_eid = (int*)take((size_t)N_EDGES * 4);
    float*              hA      = (float*)take((size_t)N_NODES * D_FEAT * 4);
    float*              hB      = (float*)take((size_t)N_NODES * D_FEAT * 4);
    float*              nh      = (float*)take((size_t)N_NODES * D_FEAT * 4);
    float*              hs      = (float*)take((size_t)N_NODES * D_FEAT * 4);
    unsigned long long* keys    = (unsigned long long*)take((size_t)N_EDGES * 8);
    unsigned int*       ghist   = (unsigned int*)take((size_t)256 * 4);
    SelState*           st      = (SelState*)take(256);
    int*                bsum    = (int*)take((size_t)SCAN_NB * 4);
    int*                boff    = (int*)take((size_t)SCAN_NB * 4);
    int*                cnt_a   = (int*)take((size_t)HC_NB * 4);
    int*                cnt_b   = (int*)take((size_t)HC_NB * 4);

    // candidate slice buffers alias dead memory during the radix passes:
    // nh is dead after coskey; hB is written only by hop-2 aggregate (after selection).
    // sizes match exactly: HC_NB*HC_SLICE*8 = 12.8 MB = N_NODES*D_FEAT*4
    unsigned long long* candA = (unsigned long long*)nh;
    unsigned long long* candB = (unsigned long long*)hB;

    hipMemsetAsync(deg, 0, (size_t)N_NODES * 4, stream);
    hipMemsetAsync(ghist, 0, (size_t)256 * 4, stream);

    deg_kernel<<<(N_EDGES + 255) / 256, 256, 0, stream>>>(dst, deg, N_EDGES);
    norm_kernel<<<(N_NODES + 255) / 256, 256, 0, stream>>>(deg, nrm, N_NODES);
    blocksum_kernel<<<SCAN_NB, 256, 0, stream>>>(deg, bsum, N_NODES);
    scanpartial_kernel<<<1, 512, 0, stream>>>(bsum, boff, SCAN_NB);
    writeoffs_kernel<<<SCAN_NB, 256, 0, stream>>>(deg, boff, offs, cursor, N_NODES);
    fill_kernel<<<(N_EDGES + 255) / 256, 256, 0, stream>>>(src, dst, cursor,
                                                           csr_src, csr_dst, csr_eid, N_EDGES);

    const float* hin = features;
    float* houts[2] = { hA, hB };
    for (int hop = 0; hop < 2; ++hop) {
        float* hout = houts[hop];
        rownorm_kernel<<<(N_NODES + 255) / 256, 256, 0, stream>>>(hin, nh, hs, nrm, N_NODES);
        initsel_kernel<<<1, 1, 0, stream>>>(st);
        coskey_kernel<<<HIST_NB, 256, 0, stream>>>(nh, csr_src, csr_dst, csr_eid,
                                                   keys, ghist, N_EDGES);
        scan8_kernel<<<1, 256, 0, stream>>>(ghist, st);   // digit 0
        for (int pass = 1; pass < 8; ++pass) {
            const unsigned long long* in =
                (pass == 1) ? keys : ((pass & 1) ? candB : candA);
            const int* cin = (pass == 1) ? (const int*)nullptr
                                         : ((pass & 1) ? cnt_b : cnt_a);
            unsigned long long* outc = (pass & 1) ? candA : candB;
            int* cout = (pass & 1) ? cnt_a : cnt_b;
            histc_kernel<<<HC_NB, 256, 0, stream>>>(in, cin, outc, cout, st, ghist, pass);
            scan8_kernel<<<1, 256, 0, stream>>>(ghist, st);
        }
        aggregate_csr_kernel<<<(N_NODES + 7) / 8, 256, 0, stream>>>(
            hs, hout, offs, csr_src, keys, st, nrm, N_NODES);
        hin = hout;
    }
    fc_kernel<<<(N_NODES + 7) / 8, 256, 0, stream>>>(hin, W, out, N_NODES);
}